// Round 17
// baseline (116.330 us; speedup 1.0000x reference)
//
#include <hip/hip_runtime.h>
#include <stdint.h>
#include <stddef.h>

// Problem: out[b,a,o] = sum_{i,j} h0[b,a,i] h1[b,a,j] T[a,i,j,o], h=concat(x,1)
// GEMM form: C[b,o] += G[b,k]*Tb[a,k,o]; main k=j*128+i (i,j<128); k=16384+c:
// G=h1[c]; k=16512+c: G=h0[c]; k=16640: G=1.
#define NA     4
#define DDIM   128
#define OUTD   128
#define BM     256
#define NTILES 261
#define TILE_B 16384          // 128 cols * 64 k * 2B (16KB per K64-tile image)
#define OUT_ELEMS (4096 * NA * OUTD)   // 2,097,152 f32
#define NKS    4              // (i-half, j-half) split -> 4 partials

typedef _Float16 f16;
typedef __attribute__((ext_vector_type(8)))  _Float16 f16x8;
typedef __attribute__((ext_vector_type(4)))  float    f32x4;

static const size_t TB_BYTES = (size_t)NA * NTILES * TILE_B;           // 17,104,896
static const size_t WS_NEED  = TB_BYTES + (size_t)NKS * OUT_ELEMS * 4; // ~50.7 MB

// ---------------------------------------------------------------------------
// Prep: T f32 -> Tb f16, per (a,tile) a 16KB image; unit v = w*128+col
// (w = k-octet 0..7) holds k = tile*64 + w*8 + e at output-col `col`.
// ---------------------------------------------------------------------------
__global__ __launch_bounds__(256) void prep_kernel(const float* __restrict__ T,
                                                   f16* __restrict__ Tb) {
    int blk  = blockIdx.x;            // a*NTILES + tile
    int a    = blk / NTILES;
    int tile = blk - a * NTILES;
    int t    = threadIdx.x;
    f16* base = Tb + (size_t)blk * (TILE_B / 2);
    #pragma unroll
    for (int u = 0; u < 4; ++u) {
        int v   = t + u * 256;
        int w   = v >> 7;
        int col = v & 127;
        f16x8 ov;
        #pragma unroll
        for (int e = 0; e < 8; ++e) {
            int k = tile * 64 + w * 8 + e;
            int i = -1, j = 0;
            if (k < 16384)       { i = k & 127;   j = k >> 7;    }
            else if (k < 16512)  { i = 128;       j = k - 16384; }
            else if (k < 16640)  { i = k - 16512; j = 128;       }
            else if (k == 16640) { i = 128;       j = 128;       }
            float val = 0.f;
            if (i >= 0) val = T[(((size_t)a * 129 + i) * 129 + j) * 128 + col];
            ov[e] = (f16)val;
        }
        *(f16x8*)(base + (size_t)v * 8) = ov;
    }
}

__device__ __forceinline__ f16x8 pack_f16x8(f32x4 a, f32x4 b) {
    f16x8 h;
    #pragma unroll
    for (int e = 0; e < 4; ++e) { h[e] = (f16)a[e]; h[e + 4] = (f16)b[e]; }
    return h;
}

// ---------------------------------------------------------------------------
// GEMM, round 17: round-14 body (nf=4, wave 64x64, 16x16x32 MFMA, 16 acc
// chains/wave, 4-deep B prefetch ring, 2 waves/SIMD) with h1 OFF the per-j
// critical path: h1t is row-major [row][64] XOR-swizzled; each 8-j group
// starts with 4 ds_read_b128 (one per mf) pulling h1[row][G*8..G*8+7] into
// registers; per-j the scalar is a static subscript h1r8[mf][pe] — zero LDS
// ops / lgkm waits inside the j loop (was 4 ds_read_u16 + wait per j, the
// suspected ~700-cyc both-pipes-idle component).
// ---------------------------------------------------------------------------
template <bool ATOMIC>
__global__ __launch_bounds__(512, 2) void gemm_kernel(const float* __restrict__ x0,
                                                      const float* __restrict__ x1,
                                                      const f16* __restrict__ Tb,
                                                      float* __restrict__ dst) {
    __shared__ __align__(16) f16 h1t[256 * 64];     // 32KB row-major swizzled

    int bid = blockIdx.x;             // 256 = 8 xcd * 32
    int xcd = bid & 7, idx = bid >> 3;
    int cls = xcd * 2 + (idx >> 4);   // 16 classes, 2 per XCD
    int mt  = idx & 15;
    int a     = cls & 3;
    int ihalf = (cls >> 2) & 1;
    int jks   = cls >> 3;
    int b0 = mt * BM;
    int jb = jks * 64;

    int t    = threadIdx.x;
    int lane = t & 63, wid = t >> 6;
    int wm   = wid >> 1, wn = wid & 1;     // 4M x 2N
    int l15  = lane & 15, g = lane >> 4;   // 16x16 frag: row/col=l15, k-octet=g

    const char* tbb = (const char*)Tb + (size_t)a * NTILES * TILE_B;

    // ---- one-time h1 window (64 j, base jb) -> LDS row-major swizzled ----
    {
        int row = t & 255, part = t >> 8;            // 2 parts x 32 c
        const float* x1r = x1 + ((size_t)(b0 + row) * NA + a) * DDIM + jb + part * 32;
        int key = (row & 7) << 3;
        #pragma unroll
        for (int q = 0; q < 8; ++q) {
            f32x4 v = *(const f32x4*)(x1r + q * 4);
            #pragma unroll
            for (int e = 0; e < 4; ++e)
                h1t[row * 64 + ((part * 32 + q * 4 + e) ^ key)] = (f16)v[e];
        }
    }
    // ---- one-time h0 -> registers: h0r[mf][s], i = ihalf*64 + s*32 + g*8 ----
    f16x8 h0r[4][2];
    #pragma unroll
    for (int mf = 0; mf < 4; ++mf) {
        int row = b0 + wm * 64 + mf * 16 + l15;
        const float* x0r = x0 + ((size_t)row * NA + a) * DDIM + ihalf * 64;
        #pragma unroll
        for (int s = 0; s < 2; ++s) {
            int ib = s * 32 + g * 8;
            h0r[mf][s] = pack_f16x8(*(const f32x4*)(x0r + ib),
                                    *(const f32x4*)(x0r + ib + 4));
        }
    }
    __syncthreads();   // h1t visible; only barrier in the kernel

    // per-lane B base: col = wn*64 + nf*16 + l15 (nf 0..3); octet = s*4+g
    const char* bp = tbb + ((size_t)g * 128 + wn * 64 + l15) * 16;
    #define BFOFF(nf, s) ((s) * 8192 + (nf) * 256)
    // main tile for j-index p (p in [0,64)): tile = 2*(jb+p) + ihalf
    #define TADR(p) (bp + (size_t)(2 * (jb + (p)) + ihalf) * TILE_B)

    f16x8 bq0[8], bq1[8], bq2[8], bq3[8];   // 4-deep ring, [nf*2+s]

    #define LOADT(BUF, P)                                                   \
    {   int np_ = (P); if (np_ > 63) np_ = 63;                              \
        const char* qq_ = TADR(np_);                                        \
        _Pragma("unroll")                                                   \
        for (int nf = 0; nf < 4; ++nf)                                      \
            _Pragma("unroll")                                               \
            for (int s = 0; s < 2; ++s)                                     \
                BUF[nf * 2 + s] = *(const f16x8*)(qq_ + BFOFF(nf, s));      \
    }

    // PE is macro-static: h1 scalar is a register subscript, no LDS access.
    #define COMPJ(BUF, PE)                                                  \
    {   __builtin_amdgcn_s_setprio(1);                                      \
        _Pragma("unroll")                                                   \
        for (int s = 0; s < 2; ++s)                                         \
            _Pragma("unroll")                                               \
            for (int mf = 0; mf < 4; ++mf) {                                \
                f16x8 af_ = h0r[mf][s] * h1r8[mf][PE];                      \
                _Pragma("unroll")                                           \
                for (int nf = 0; nf < 4; ++nf)                              \
                    acc[mf][nf] = __builtin_amdgcn_mfma_f32_16x16x32_f16(   \
                        af_, BUF[nf * 2 + s], acc[mf][nf], 0, 0, 0);        \
            }                                                               \
        __builtin_amdgcn_s_setprio(0);                                      \
    }

    // prologue: fill the ring with j = 0..3
    LOADT(bq0, 0) LOADT(bq1, 1) LOADT(bq2, 2) LOADT(bq3, 3)

    f32x4 acc[4][4];
    #pragma unroll
    for (int mf = 0; mf < 4; ++mf)
        #pragma unroll
        for (int nf = 0; nf < 4; ++nf) acc[mf][nf] = (f32x4)0.f;

    // ---- main loop: 8 groups x 8 j's; h1 via 4 ds_read_b128 per group ----
    #pragma unroll 1
    for (int G = 0; G < 8; ++G) {
        int p0 = G * 8;
        f16x8 h1r8[4];
        #pragma unroll
        for (int mf = 0; mf < 4; ++mf) {
            int row = wm * 64 + mf * 16 + l15;
            h1r8[mf] = *(const f16x8*)&h1t[row * 64 + (p0 ^ ((row & 7) << 3))];
        }
        COMPJ(bq0, 0) LOADT(bq0, p0 + 4)
        COMPJ(bq1, 1) LOADT(bq1, p0 + 5)
        COMPJ(bq2, 2) LOADT(bq2, p0 + 6)
        COMPJ(bq3, 3) LOADT(bq3, p0 + 7)
        COMPJ(bq0, 4) LOADT(bq0, p0 + 8)
        COMPJ(bq1, 5) LOADT(bq1, p0 + 9)
        COMPJ(bq2, 6) LOADT(bq2, p0 + 10)
        COMPJ(bq3, 7) LOADT(bq3, p0 + 11)
    }

    // ---- correction tail per class ----
    int ct0, ct1, ncorr;
    if (ihalf == 0 && jks == 0)      { ct0 = 256; ct1 = 258; ncorr = 2; }
    else if (ihalf == 0 && jks == 1) { ct0 = 257; ct1 = 0;   ncorr = 1; }
    else if (ihalf == 1 && jks == 0) { ct0 = 259; ct1 = 0;   ncorr = 1; }
    else                             { ct0 = 260; ct1 = 0;   ncorr = 1; }
    for (int cc = 0; cc < ncorr; ++cc) {
        int tile = (cc == 0) ? ct0 : ct1;
        const char* qq = tbb + (size_t)tile * TILE_B
                       + ((size_t)g * 128 + wn * 64 + l15) * 16;
        f16x8 bt[8];
        #pragma unroll
        for (int nf = 0; nf < 4; ++nf)
            #pragma unroll
            for (int s = 0; s < 2; ++s)
                bt[nf * 2 + s] = *(const f16x8*)(qq + BFOFF(nf, s));

        #pragma unroll
        for (int s = 0; s < 2; ++s)
            #pragma unroll
            for (int mf = 0; mf < 4; ++mf) {
                int row = wm * 64 + mf * 16 + l15;
                f16x8 af;
                if (tile == 256 || tile == 257) {        // j-corr: G = h1[window c]
                    int c0 = (s * 32 + g * 8) ^ ((row & 7) << 3);
                    af = *(const f16x8*)&h1t[row * 64 + c0];
                } else if (tile == 258 || tile == 259) { // i-corr: G = h0[ihalf*64+c]
                    af = h0r[mf][s];
                } else {                                 // 260: G = 1 at k_local 0
                    af = (f16x8)(f16)0.f;
                    if (s == 0 && g == 0) af[0] = (f16)1.f;
                }
                #pragma unroll
                for (int nf = 0; nf < 4; ++nf)
                    acc[mf][nf] = __builtin_amdgcn_mfma_f32_16x16x32_f16(
                        af, bt[nf * 2 + s], acc[mf][nf], 0, 0, 0);
            }
    }

    // ---- epilogue: 16x16 C/D layout col=lane&15, row=(lane>>4)*4+r ----
    int clsk = ihalf * 2 + jks;
    float* base = ATOMIC ? dst : dst + (size_t)clsk * OUT_ELEMS;
    #pragma unroll
    for (int mf = 0; mf < 4; ++mf)
        #pragma unroll
        for (int nf = 0; nf < 4; ++nf)
            #pragma unroll
            for (int r = 0; r < 4; ++r) {
                int orow = b0 + wm * 64 + mf * 16 + g * 4 + r;
                int ocol = wn * 64 + nf * 16 + l15;
                size_t off = ((size_t)orow * NA + a) * OUTD + ocol;
                if (ATOMIC) unsafeAtomicAdd(&base[off], acc[mf][nf][r]);
                else        base[off] = acc[mf][nf][r];
            }
    #undef BFOFF
    #undef TADR
    #undef LOADT
    #undef COMPJ
}

// ---------------------------------------------------------------------------
// Reduce: out = P0 + P1 + P2 + P3 (f32x4 vectorized)
// ---------------------------------------------------------------------------
__global__ __launch_bounds__(256) void reduce_kernel(const float* __restrict__ P,
                                                     float* __restrict__ out) {
    int i = blockIdx.x * 256 + threadIdx.x;     // 524288 vec4 elems
    f32x4 s = ((const f32x4*)P)[i];
    #pragma unroll
    for (int k = 1; k < NKS; ++k)
        s += ((const f32x4*)(P + (size_t)k * OUT_ELEMS))[i];
    ((f32x4*)out)[i] = s;
}

// ---------------------------------------------------------------------------
// Fallback (ws too small): naive but correct f32 kernel.
// ---------------------------------------------------------------------------
__global__ __launch_bounds__(128) void fallback_kernel(const float* __restrict__ x0,
                                                       const float* __restrict__ x1,
                                                       const float* __restrict__ T,
                                                       float* __restrict__ out) {
    int ba = blockIdx.x;
    int b = ba >> 2, a = ba & 3;
    int o = threadIdx.x;
    const float* h0 = x0 + ((size_t)b * NA + a) * DDIM;
    const float* h1 = x1 + ((size_t)b * NA + a) * DDIM;
    float acc = 0.f;
    for (int i = 0; i < 129; ++i) {
        float h0i = (i < 128) ? h0[i] : 1.f;
        const float* Trow = T + (((size_t)a * 129 + i) * 129) * 128 + o;
        float part = 0.f;
        for (int j = 0; j < 129; ++j) {
            float h1j = (j < 128) ? h1[j] : 1.f;
            part += h1j * Trow[(size_t)j * 128];
        }
        acc += h0i * part;
    }
    out[((size_t)b * NA + a) * OUTD + o] = acc;
}

extern "C" void kernel_launch(void* const* d_in, const int* in_sizes, int n_in,
                              void* d_out, int out_size, void* d_ws, size_t ws_size,
                              hipStream_t stream) {
    const float* x0 = (const float*)d_in[0];
    const float* x1 = (const float*)d_in[1];
    const float* T  = (const float*)d_in[2];
    float* out = (float*)d_out;

    if (ws_size < TB_BYTES) {
        fallback_kernel<<<4096 * NA, 128, 0, stream>>>(x0, x1, T, out);
        return;
    }

    f16* Tb = (f16*)d_ws;
    prep_kernel<<<NA * NTILES, 256, 0, stream>>>(T, Tb);

    if (ws_size >= WS_NEED) {
        float* P = (float*)((char*)d_ws + TB_BYTES);
        gemm_kernel<false><<<256, 512, 0, stream>>>(x0, x1, Tb, P);
        reduce_kernel<<<OUT_ELEMS / 4 / 256, 256, 0, stream>>>(P, out);
    } else {
        hipMemsetAsync(d_out, 0, (size_t)out_size * sizeof(float), stream);
        gemm_kernel<true><<<256, 512, 0, stream>>>(x0, x1, Tb, out);
    }
}

// Round 18
// 90.713 us; speedup vs baseline: 1.2824x; 1.2824x over previous
//
#include <hip/hip_runtime.h>
#include <stdint.h>
#include <stddef.h>

// Problem: out[b,a,o] = sum_{i,j} h0[b,a,i] h1[b,a,j] T[a,i,j,o], h=concat(x,1)
// GEMM form: C[b,o] += G[b,k]*Tb[a,k,o]; main k=j*128+i (i,j<128); k=16384+c:
// G=h1[c]; k=16512+c: G=h0[c]; k=16640: G=1.
#define NA     4
#define DDIM   128
#define OUTD   128
#define BM     256
#define NTILES 261
#define TILE_B 16384          // 128 cols * 64 k * 2B (16KB per K64-tile image)
#define OUT_ELEMS (4096 * NA * OUTD)   // 2,097,152 f32
#define NKS    4              // (i-half, j-half) split -> 4 partials

typedef _Float16 f16;
typedef __attribute__((ext_vector_type(8)))  _Float16 f16x8;
typedef __attribute__((ext_vector_type(4)))  float    f32x4;

static const size_t TB_BYTES = (size_t)NA * NTILES * TILE_B;           // 17,104,896
static const size_t WS_NEED  = TB_BYTES + (size_t)NKS * OUT_ELEMS * 4; // ~50.7 MB

// ---------------------------------------------------------------------------
// Prep: T f32 -> Tb f16, per (a,tile) a 16KB image; unit v = w*128+col
// (w = k-octet 0..7) holds k = tile*64 + w*8 + e at output-col `col`.
// ---------------------------------------------------------------------------
__global__ __launch_bounds__(256) void prep_kernel(const float* __restrict__ T,
                                                   f16* __restrict__ Tb) {
    int blk  = blockIdx.x;            // a*NTILES + tile
    int a    = blk / NTILES;
    int tile = blk - a * NTILES;
    int t    = threadIdx.x;
    f16* base = Tb + (size_t)blk * (TILE_B / 2);
    #pragma unroll
    for (int u = 0; u < 4; ++u) {
        int v   = t + u * 256;
        int w   = v >> 7;
        int col = v & 127;
        f16x8 ov;
        #pragma unroll
        for (int e = 0; e < 8; ++e) {
            int k = tile * 64 + w * 8 + e;
            int i = -1, j = 0;
            if (k < 16384)       { i = k & 127;   j = k >> 7;    }
            else if (k < 16512)  { i = 128;       j = k - 16384; }
            else if (k < 16640)  { i = k - 16512; j = 128;       }
            else if (k == 16640) { i = 128;       j = 128;       }
            float val = 0.f;
            if (i >= 0) val = T[(((size_t)a * 129 + i) * 129 + j) * 128 + col];
            ov[e] = (f16)val;
        }
        *(f16x8*)(base + (size_t)v * 8) = ov;
    }
}

__device__ __forceinline__ f16x8 pack_f16x8(f32x4 a, f32x4 b) {
    f16x8 h;
    #pragma unroll
    for (int e = 0; e < 4; ++e) { h[e] = (f16)a[e]; h[e + 4] = (f16)b[e]; }
    return h;
}

// ---------------------------------------------------------------------------
// GEMM (round-14 configuration — measured best: gemm 70.0us, MfmaUtil 45%,
// VGPR 120 + 64 AGPR, no spill, 2 waves/SIMD):
// nf=4, wave = 64 rows x 64 cols, 16x16x32 MFMA, 16 acc chains/wave,
// BM=256, 8 waves (4M x 2N), grid 256 = 1 block/CU, 4-deep B prefetch
// ring (reuse distance ~3 bursts >> L2 latency). A built in registers
// (h0 stationary, h1 scalar from LDS). K split (i-half, j-half) -> 4
// partials + reduce (no atomics).
// ---------------------------------------------------------------------------
template <bool ATOMIC>
__global__ __launch_bounds__(512, 2) void gemm_kernel(const float* __restrict__ x0,
                                                      const float* __restrict__ x1,
                                                      const f16* __restrict__ Tb,
                                                      float* __restrict__ dst) {
    __shared__ __align__(16) f16 h1t[64 * 256];     // 32KB: h1t[c][row], c = j - jb

    int bid = blockIdx.x;             // 256 = 8 xcd * 32
    int xcd = bid & 7, idx = bid >> 3;
    int cls = xcd * 2 + (idx >> 4);   // 16 classes, 2 per XCD
    int mt  = idx & 15;
    int a     = cls & 3;
    int ihalf = (cls >> 2) & 1;
    int jks   = cls >> 3;
    int b0 = mt * BM;
    int jb = jks * 64;

    int t    = threadIdx.x;
    int lane = t & 63, wid = t >> 6;
    int wm   = wid >> 1, wn = wid & 1;     // 4M x 2N
    int l15  = lane & 15, g = lane >> 4;   // 16x16 frag: row/col=l15, k-octet=g

    const char* tbb = (const char*)Tb + (size_t)a * NTILES * TILE_B;

    // ---- one-time h1 window (64 j, base jb) -> LDS transposed ----
    {
        int row = t & 255, part = t >> 8;            // 2 parts x 32 c
        const float* x1r = x1 + ((size_t)(b0 + row) * NA + a) * DDIM + jb + part * 32;
        #pragma unroll
        for (int q = 0; q < 8; ++q) {
            f32x4 v = *(const f32x4*)(x1r + q * 4);
            #pragma unroll
            for (int e = 0; e < 4; ++e)
                h1t[(part * 32 + q * 4 + e) * 256 + row] = (f16)v[e];
        }
    }
    // ---- one-time h0 -> registers: h0r[mf][s], i = ihalf*64 + s*32 + g*8 ----
    f16x8 h0r[4][2];
    #pragma unroll
    for (int mf = 0; mf < 4; ++mf) {
        int row = b0 + wm * 64 + mf * 16 + l15;
        const float* x0r = x0 + ((size_t)row * NA + a) * DDIM + ihalf * 64;
        #pragma unroll
        for (int s = 0; s < 2; ++s) {
            int ib = s * 32 + g * 8;
            h0r[mf][s] = pack_f16x8(*(const f32x4*)(x0r + ib),
                                    *(const f32x4*)(x0r + ib + 4));
        }
    }
    __syncthreads();   // h1t visible; only barrier in the kernel

    // per-lane B base: col = wn*64 + nf*16 + l15 (nf 0..3); octet = s*4+g
    const char* bp = tbb + ((size_t)g * 128 + wn * 64 + l15) * 16;
    #define BFOFF(nf, s) ((s) * 8192 + (nf) * 256)
    // main tile for j-index p (p in [0,64)): tile = 2*(jb+p) + ihalf
    #define TADR(p) (bp + (size_t)(2 * (jb + (p)) + ihalf) * TILE_B)

    f16x8 bq0[8], bq1[8], bq2[8], bq3[8];   // 4-deep ring, [nf*2+s]

    #define LOADT(BUF, P)                                                   \
    {   int np_ = (P); if (np_ > 63) np_ = 63;                              \
        const char* qq_ = TADR(np_);                                        \
        _Pragma("unroll")                                                   \
        for (int nf = 0; nf < 4; ++nf)                                      \
            _Pragma("unroll")                                               \
            for (int s = 0; s < 2; ++s)                                     \
                BUF[nf * 2 + s] = *(const f16x8*)(qq_ + BFOFF(nf, s));      \
    }

    #define COMPJ(BUF, P)                                                   \
    {   f16 h1v_[4];                                                        \
        _Pragma("unroll")                                                   \
        for (int mf = 0; mf < 4; ++mf)                                      \
            h1v_[mf] = h1t[(P) * 256 + wm * 64 + mf * 16 + l15];            \
        __builtin_amdgcn_s_setprio(1);                                      \
        _Pragma("unroll")                                                   \
        for (int s = 0; s < 2; ++s)                                         \
            _Pragma("unroll")                                               \
            for (int mf = 0; mf < 4; ++mf) {                                \
                f16x8 af_ = h0r[mf][s] * h1v_[mf];                          \
                _Pragma("unroll")                                           \
                for (int nf = 0; nf < 4; ++nf)                              \
                    acc[mf][nf] = __builtin_amdgcn_mfma_f32_16x16x32_f16(   \
                        af_, BUF[nf * 2 + s], acc[mf][nf], 0, 0, 0);        \
            }                                                               \
        __builtin_amdgcn_s_setprio(0);                                      \
    }

    // prologue: fill the ring with j = 0..3
    LOADT(bq0, 0) LOADT(bq1, 1) LOADT(bq2, 2) LOADT(bq3, 3)

    f32x4 acc[4][4];
    #pragma unroll
    for (int mf = 0; mf < 4; ++mf)
        #pragma unroll
        for (int nf = 0; nf < 4; ++nf) acc[mf][nf] = (f32x4)0.f;

    // ---- main loop: 64 j's as 16 iterations of 4, 4-deep prefetch ----
    #pragma unroll 1
    for (int q = 0; q < 16; ++q) {
        int p0 = 4 * q;
        COMPJ(bq0, p0)     LOADT(bq0, p0 + 4)
        COMPJ(bq1, p0 + 1) LOADT(bq1, p0 + 5)
        COMPJ(bq2, p0 + 2) LOADT(bq2, p0 + 6)
        COMPJ(bq3, p0 + 3) LOADT(bq3, p0 + 7)
    }

    // ---- correction tail per class ----
    int ct0, ct1, ncorr;
    if (ihalf == 0 && jks == 0)      { ct0 = 256; ct1 = 258; ncorr = 2; }
    else if (ihalf == 0 && jks == 1) { ct0 = 257; ct1 = 0;   ncorr = 1; }
    else if (ihalf == 1 && jks == 0) { ct0 = 259; ct1 = 0;   ncorr = 1; }
    else                             { ct0 = 260; ct1 = 0;   ncorr = 1; }
    for (int cc = 0; cc < ncorr; ++cc) {
        int tile = (cc == 0) ? ct0 : ct1;
        const char* qq = tbb + (size_t)tile * TILE_B
                       + ((size_t)g * 128 + wn * 64 + l15) * 16;
        f16x8 bt[8];
        #pragma unroll
        for (int nf = 0; nf < 4; ++nf)
            #pragma unroll
            for (int s = 0; s < 2; ++s)
                bt[nf * 2 + s] = *(const f16x8*)(qq + BFOFF(nf, s));

        #pragma unroll
        for (int s = 0; s < 2; ++s)
            #pragma unroll
            for (int mf = 0; mf < 4; ++mf) {
                int row = wm * 64 + mf * 16 + l15;
                f16x8 af;
                if (tile == 256 || tile == 257) {        // j-corr: G = h1[jb + c]
                    #pragma unroll
                    for (int e = 0; e < 8; ++e)
                        af[e] = h1t[(s * 32 + g * 8 + e) * 256 + row];
                } else if (tile == 258 || tile == 259) { // i-corr: G = h0[ihalf*64 + c]
                    af = h0r[mf][s];
                } else {                                 // 260: G = 1 at k_local 0
                    af = (f16x8)(f16)0.f;
                    if (s == 0 && g == 0) af[0] = (f16)1.f;
                }
                #pragma unroll
                for (int nf = 0; nf < 4; ++nf)
                    acc[mf][nf] = __builtin_amdgcn_mfma_f32_16x16x32_f16(
                        af, bt[nf * 2 + s], acc[mf][nf], 0, 0, 0);
            }
    }

    // ---- epilogue: 16x16 C/D layout col=lane&15, row=(lane>>4)*4+r ----
    int clsk = ihalf * 2 + jks;
    float* base = ATOMIC ? dst : dst + (size_t)clsk * OUT_ELEMS;
    #pragma unroll
    for (int mf = 0; mf < 4; ++mf)
        #pragma unroll
        for (int nf = 0; nf < 4; ++nf)
            #pragma unroll
            for (int r = 0; r < 4; ++r) {
                int orow = b0 + wm * 64 + mf * 16 + g * 4 + r;
                int ocol = wn * 64 + nf * 16 + l15;
                size_t off = ((size_t)orow * NA + a) * OUTD + ocol;
                if (ATOMIC) unsafeAtomicAdd(&base[off], acc[mf][nf][r]);
                else        base[off] = acc[mf][nf][r];
            }
    #undef BFOFF
    #undef TADR
    #undef LOADT
    #undef COMPJ
}

// ---------------------------------------------------------------------------
// Reduce: out = P0 + P1 + P2 + P3 (f32x4 vectorized)
// ---------------------------------------------------------------------------
__global__ __launch_bounds__(256) void reduce_kernel(const float* __restrict__ P,
                                                     float* __restrict__ out) {
    int i = blockIdx.x * 256 + threadIdx.x;     // 524288 vec4 elems
    f32x4 s = ((const f32x4*)P)[i];
    #pragma unroll
    for (int k = 1; k < NKS; ++k)
        s += ((const f32x4*)(P + (size_t)k * OUT_ELEMS))[i];
    ((f32x4*)out)[i] = s;
}

// ---------------------------------------------------------------------------
// Fallback (ws too small): naive but correct f32 kernel.
// ---------------------------------------------------------------------------
__global__ __launch_bounds__(128) void fallback_kernel(const float* __restrict__ x0,
                                                       const float* __restrict__ x1,
                                                       const float* __restrict__ T,
                                                       float* __restrict__ out) {
    int ba = blockIdx.x;
    int b = ba >> 2, a = ba & 3;
    int o = threadIdx.x;
    const float* h0 = x0 + ((size_t)b * NA + a) * DDIM;
    const float* h1 = x1 + ((size_t)b * NA + a) * DDIM;
    float acc = 0.f;
    for (int i = 0; i < 129; ++i) {
        float h0i = (i < 128) ? h0[i] : 1.f;
        const float* Trow = T + (((size_t)a * 129 + i) * 129) * 128 + o;
        float part = 0.f;
        for (int j = 0; j < 129; ++j) {
            float h1j = (j < 128) ? h1[j] : 1.f;
            part += h1j * Trow[(size_t)j * 128];
        }
        acc += h0i * part;
    }
    out[((size_t)b * NA + a) * OUTD + o] = acc;
}

extern "C" void kernel_launch(void* const* d_in, const int* in_sizes, int n_in,
                              void* d_out, int out_size, void* d_ws, size_t ws_size,
                              hipStream_t stream) {
    const float* x0 = (const float*)d_in[0];
    const float* x1 = (const float*)d_in[1];
    const float* T  = (const float*)d_in[2];
    float* out = (float*)d_out;

    if (ws_size < TB_BYTES) {
        fallback_kernel<<<4096 * NA, 128, 0, stream>>>(x0, x1, T, out);
        return;
    }

    f16* Tb = (f16*)d_ws;
    prep_kernel<<<NA * NTILES, 256, 0, stream>>>(T, Tb);

    if (ws_size >= WS_NEED) {
        float* P = (float*)((char*)d_ws + TB_BYTES);
        gemm_kernel<false><<<256, 512, 0, stream>>>(x0, x1, Tb, P);
        reduce_kernel<<<OUT_ELEMS / 4 / 256, 256, 0, stream>>>(P, out);
    } else {
        hipMemsetAsync(d_out, 0, (size_t)out_size * sizeof(float), stream);
        gemm_kernel<true><<<256, 512, 0, stream>>>(x0, x1, Tb, out);
    }
}